// Round 14
// baseline (1447.647 us; speedup 1.0000x reference)
//
#include <hip/hip_runtime.h>
#include <stdint.h>

#define HHH 50
#define WWW 76
#define NPIX 3800
#define NA 34200
#define PRE 6000
#define POST 300
#define NW 94            // ceil(6000/64)
#define CIN 512
#define COUT 512
#define NBATCH 4
#define NGT 20
#define TFHALF 68400u    // (4*34200)/2
#define XTB 2252800      // 275 pg * 64 cg * 16 po * 8 cl (elems per batch per split)

typedef __bf16 bf16x8 __attribute__((ext_vector_type(8)));
typedef float f32x4 __attribute__((ext_vector_type(4)));
typedef unsigned int u32x4v __attribute__((ext_vector_type(4)));

__device__ static inline f32x4 MFMA16(bf16x8 a, bf16x8 b, f32x4 c) {
  return __builtin_amdgcn_mfma_f32_16x16x32_bf16(a, b, c, 0, 0, 0);
}
__device__ static inline bf16x8 LD8(const unsigned short* p) {
  return __builtin_bit_cast(bf16x8, *(const u32x4v*)p);
}

// ---------------- threefry2x32 (exact JAX lowering) ----------------
__host__ __device__ static inline void tf2x32(unsigned k0, unsigned k1, unsigned& x0, unsigned& x1) {
  unsigned k2 = k0 ^ k1 ^ 0x1BD11BDAu;
#define TFR(r) do { x0 += x1; x1 = (x1 << (r)) | (x1 >> (32 - (r))); x1 ^= x0; } while (0)
  x0 += k0; x1 += k1;
  TFR(13); TFR(15); TFR(26); TFR(6);
  x0 += k1; x1 += k2 + 1u;
  TFR(17); TFR(29); TFR(16); TFR(24);
  x0 += k2; x1 += k0 + 2u;
  TFR(13); TFR(15); TFR(26); TFR(6);
  x0 += k0; x1 += k1 + 3u;
  TFR(17); TFR(29); TFR(16); TFR(24);
  x0 += k1; x1 += k2 + 4u;
  TFR(13); TFR(15); TFR(26); TFR(6);
  x0 += k2; x1 += k0 + 5u;
#undef TFR
}

__device__ static inline unsigned tf_u23(unsigned k0, unsigned k1, unsigned p) {
  unsigned x0, x1;
  if (p < TFHALF) { x0 = p; x1 = p + TFHALF; tf2x32(k0, k1, x0, x1); return x0 >> 9; }
  x0 = p - TFHALF; x1 = p; tf2x32(k0, k1, x0, x1); return x1 >> 9;
}

// base anchors (scales 8/16/32 x ratios .5/1/2, ratio-major)
__device__ const float BA[9][4] = {
  {-84.f, -40.f,  99.f,  55.f}, {-176.f, -88.f, 191.f, 103.f}, {-360.f, -184.f, 375.f, 199.f},
  {-56.f, -56.f,  71.f,  71.f}, {-120.f, -120.f, 135.f, 135.f}, {-248.f, -248.f, 263.f, 263.f},
  {-36.f, -80.f,  51.f,  95.f}, {-80.f, -168.f,  95.f, 183.f}, {-168.f, -344.f, 183.f, 359.f}
};

__device__ static inline unsigned monoF(float f) {
  int b = __float_as_int(f);
  unsigned u = (unsigned)b;
  return (b < 0) ? ~u : (u | 0x80000000u);
}
__device__ static inline float unmonoF(unsigned u) {
  unsigned b = (u & 0x80000000u) ? (u ^ 0x80000000u) : ~u;
  return __int_as_float((int)b);
}

// exact 3-way bf16 split: v == h + m + l
__device__ static inline void split3(float v, unsigned short& h, unsigned short& m, unsigned short& l) {
  __bf16 b0 = (__bf16)v;  float f0 = (float)b0;
  float r = v - f0;       __bf16 b1 = (__bf16)r;  float f1 = (float)b1;
  float r2 = r - f1;      __bf16 b2 = (__bf16)r2;
  h = __builtin_bit_cast(unsigned short, b0);
  m = __builtin_bit_cast(unsigned short, b1);
  l = __builtin_bit_cast(unsigned short, b2);
}

// ---------------- X split: coalesced via LDS plane image ----------------
// block = (cg, b): stages its 8 ci rows row-major coalesced into a zero-padded
// LDS plane (8 x 4401 f32 = 137.5 KB), then streams the fragment layout out
// fully coalesced (128 consecutive elems per pg-chunk).
__global__ __launch_bounds__(256) void k_split_x(const float* __restrict__ feat,
                                                 unsigned short* __restrict__ x0,
                                                 unsigned short* __restrict__ x1,
                                                 unsigned short* __restrict__ x2) {
  __shared__ float ldsb[8 * 4401];
  const int cg = blockIdx.x, b = blockIdx.y;
  const int t = threadIdx.x;
  for (int e = t; e < 8 * 4401; e += 256) ldsb[e] = 0.f;
  __syncthreads();
  const float* fb = feat + ((size_t)(b * 512 + cg * 8)) * NPIX;
#pragma unroll
  for (int r = 0; r < 8; ++r) {
    for (int i = t; i < NPIX; i += 256) {
      int h = i / 76, w = i - h * 76;
      ldsb[r * 4401 + (h + 2) * 80 + w + 1] = fb[(size_t)r * NPIX + i];
    }
  }
  __syncthreads();
  const size_t obase = (size_t)b * XTB + (size_t)cg * 128;
  for (int pgb = 0; pgb < 276; pgb += 2) {
    int pg = pgb + (t >> 7);
    int e = t & 127;
    if (pg < 275) {
      int po = e >> 3, cl = e & 7;
      int px = pg * 16 + po;
      float v = ldsb[cl * 4401 + px];
      unsigned short hh, mm, ll;
      split3(v, hh, mm, ll);
      size_t o = obase + (size_t)pg * 8192 + e;
      x0[o] = hh; x1[o] = mm; x2[o] = ll;
    }
  }
}

// ---------------- W split (+ absorbed init): WT_s[tap][cg 64][co 512][cl 8] bf16 ----------------
__global__ void k_split_w(const float* __restrict__ cw, unsigned short* __restrict__ w0,
                          unsigned short* __restrict__ w1, unsigned short* __restrict__ w2,
                          unsigned* __restrict__ gtmaxU, int* __restrict__ cnts, float* __restrict__ accums) {
  int tid = blockIdx.x * 256 + threadIdx.x;
  if (blockIdx.x == 0) {
    int t = threadIdx.x;
    if (t < NBATCH * NGT) gtmaxU[t] = 0x407FFFFFu;  // mono(-1.0f)
    if (t < 8) cnts[t] = 0;
    if (t < 8) accums[t] = 0.f;
  }
  if (tid >= 9 * 64 * 512 * 8) return;
  int cl = tid & 7;
  int co = (tid >> 3) & 511;
  int cg = (tid >> 12) & 63;
  int tap = tid >> 18;
  int ci = cg * 8 + cl;
  float v = cw[((size_t)co * 512 + ci) * 9 + tap];
  unsigned short h, m, l;
  split3(v, h, m, l);
  w0[tid] = h; w1[tid] = m; w2[tid] = l;
}

__global__ void k_tr_w1(const float* __restrict__ clsw, const float* __restrict__ bbw, float* __restrict__ wt1) {
  int tid = blockIdx.x * 256 + threadIdx.x;
  if (tid >= CIN * 64) return;
  int c = tid & 63, ci = tid >> 6;
  float v = 0.f;
  if (c < 18) v = clsw[c * 512 + ci];
  else if (c < 54) v = bbw[(c - 18) * 512 + ci];
  wt1[tid] = v;  // [ci][64]
}

// ---------------- conv 3x3 + ReLU via 3-split bf16 MFMA — FROZEN round-9 form ----------------
// f64 masters folded every 2 kg. ERRATA r6: (256,3) reg-cap -> spill (+373us).
// ERRATA r12: f32 fold-every-kg -> dependency join per kg, 517->722us. Do not restructure.
__global__ __launch_bounds__(256, 2) void k_conv3(
    const unsigned short* __restrict__ XT0, const unsigned short* __restrict__ XT1,
    const unsigned short* __restrict__ XT2,
    const unsigned short* __restrict__ WT0, const unsigned short* __restrict__ WT1,
    const unsigned short* __restrict__ WT2,
    const float* __restrict__ bias, float* __restrict__ out) {
  const int d = blockIdx.x;
  const int copair = (d >> 1) & 3, half = d & 1, g = d >> 3;
  const int cob = copair * 2 + (g & 1);
  const int pxb = half * 64 + (g >> 1);
  const int pxp = pxb & 31, b = pxb >> 5;
  const int co0 = cob * 64;
  const int px0 = 160 + pxp * 128;
  const int t = threadIdx.x, l = t & 63, wv = t >> 6;
  const int wr = wv >> 1, wc = wv & 1;
  const int l15 = l & 15, lq = l >> 4;
  f32x4 cmain[2][4], ccorr[2][4];
  double accd[2][4][4];
#pragma unroll
  for (int c = 0; c < 2; ++c)
#pragma unroll
    for (int p = 0; p < 4; ++p) {
      cmain[c][p] = (f32x4)(0.f); ccorr[c][p] = (f32x4)(0.f);
#pragma unroll
      for (int r = 0; r < 4; ++r) accd[c][p][r] = 0.0;
    }
  const unsigned short* xt0 = XT0 + (size_t)b * XTB;
  const unsigned short* xt1 = XT1 + (size_t)b * XTB;
  const unsigned short* xt2 = XT2 + (size_t)b * XTB;
  const int coA = wr * 32 + l15;
  const int OFFT[9] = {-81, -80, -79, -1, 0, 1, 79, 80, 81};
  const int pxw = px0 + wc * 64 + l15;

  for (int kg = 0; kg < 16; ++kg) {
    const int cgl = kg * 4 + lq;
    const int cglo = cgl * 128;
    const size_t aro = ((size_t)cgl * 512 + co0 + coA) * 8;
#pragma unroll
    for (int tap = 0; tap < 9; ++tap) {
      const size_t ao = aro + (size_t)tap * (64 * 512 * 8);
      bf16x8 A0[2], A1[2], A2[2];
      A0[0] = LD8(WT0 + ao); A0[1] = LD8(WT0 + ao + 128);
      A1[0] = LD8(WT1 + ao); A1[1] = LD8(WT1 + ao + 128);
      A2[0] = LD8(WT2 + ao); A2[1] = LD8(WT2 + ao + 128);
      const int pxbase = pxw + OFFT[tap];
      const size_t eob = (size_t)((pxbase >> 4) * 8192 + (pxbase & 15) * 8 + cglo);
#pragma unroll
      for (int p = 0; p < 4; ++p) {
        const size_t eo = eob + (size_t)p * 8192;
        bf16x8 B0 = LD8(xt0 + eo);
        bf16x8 B1 = LD8(xt1 + eo);
        bf16x8 B2 = LD8(xt2 + eo);
#pragma unroll
        for (int c = 0; c < 2; ++c) {
          cmain[c][p] = MFMA16(A0[c], B0, cmain[c][p]);
          ccorr[c][p] = MFMA16(A2[c], B0, ccorr[c][p]);
          ccorr[c][p] = MFMA16(A0[c], B2, ccorr[c][p]);
          ccorr[c][p] = MFMA16(A1[c], B1, ccorr[c][p]);
          ccorr[c][p] = MFMA16(A1[c], B0, ccorr[c][p]);
          ccorr[c][p] = MFMA16(A0[c], B1, ccorr[c][p]);
        }
      }
    }
    if (kg & 1) {  // fold K=64ci x 9tap window into f64 masters
#pragma unroll
      for (int c = 0; c < 2; ++c)
#pragma unroll
        for (int p = 0; p < 4; ++p) {
#pragma unroll
          for (int r = 0; r < 4; ++r) accd[c][p][r] += (double)cmain[c][p][r];
          cmain[c][p] = (f32x4)(0.f);
        }
    }
  }
  const size_t outb = ((size_t)b * 512 + co0) * NPIX;
#pragma unroll
  for (int c = 0; c < 2; ++c)
#pragma unroll
    for (int p = 0; p < 4; ++p)
#pragma unroll
      for (int r = 0; r < 4; ++r) {
        int coL = wr * 32 + c * 16 + lq * 4 + r;
        int px = px0 + wc * 64 + p * 16 + l15;
        int hq = px / 80, wq = px - hq * 80;
        if (hq >= 2 && hq < 52 && wq >= 1 && wq < 77) {
          float v = (float)(accd[c][p][r] + (double)ccorr[c][p][r]) + bias[co0 + coL];
          out[outb + (size_t)coL * NPIX + (hq - 2) * 76 + (wq - 1)] = fmaxf(v, 0.f);
        }
      }
}

// ---------------- 1x1 convs: cls(18) + bbox(36) fused, f64 chunk accumulation ----------------
__global__ __launch_bounds__(256) void k_conv1(const float* __restrict__ x, const float* __restrict__ wt1,
                                               const float* __restrict__ clsb, const float* __restrict__ bbb,
                                               float* __restrict__ clsS, float* __restrict__ bbp) {
  const int b = blockIdx.y;
  const int px0 = blockIdx.x * 128;
  const int t = threadIdx.x;
  const int cg = t & 7, pg = t >> 3;
  __shared__ float xs[16][128];
  __shared__ float ws[16][72];
  double acc[8][4];
#pragma unroll
  for (int i = 0; i < 8; ++i)
#pragma unroll
    for (int j = 0; j < 4; ++j) acc[i][j] = 0.0;
  const float* xb = x + (size_t)b * CIN * NPIX;
  for (int cc = 0; cc < CIN; cc += 16) {
#pragma unroll
    for (int e0 = 0; e0 < 8; ++e0) {
      int e = t + e0 * 256;
      int r = e >> 7, c = e & 127;
      int p = px0 + c;
      xs[r][c] = (p < NPIX) ? xb[(size_t)(cc + r) * NPIX + p] : 0.f;
    }
#pragma unroll
    for (int e0 = 0; e0 < 4; ++e0) {
      int e = t + e0 * 256;
      int r = e >> 6, c = e & 63;
      ws[r][c + ((c >> 5) << 2)] = wt1[(cc + r) * 64 + c];
    }
    __syncthreads();
    const int wcol = (cg << 3) + ((cg >> 2) << 2);
    const int xcol = pg << 2;
    float a32[8][4];
#pragma unroll
    for (int i = 0; i < 8; ++i)
#pragma unroll
      for (int j = 0; j < 4; ++j) a32[i][j] = 0.f;
#pragma unroll
    for (int k = 0; k < 16; ++k) {
      const float4 w0 = *(const float4*)&ws[k][wcol];
      const float4 w1 = *(const float4*)&ws[k][wcol + 4];
      const float4 xa = *(const float4*)&xs[k][xcol];
      const float wv[8] = {w0.x, w0.y, w0.z, w0.w, w1.x, w1.y, w1.z, w1.w};
      const float xv[4] = {xa.x, xa.y, xa.z, xa.w};
#pragma unroll
      for (int i = 0; i < 8; ++i)
#pragma unroll
        for (int j = 0; j < 4; ++j)
          a32[i][j] = fmaf(wv[i], xv[j], a32[i][j]);
    }
#pragma unroll
    for (int i = 0; i < 8; ++i)
#pragma unroll
      for (int j = 0; j < 4; ++j) acc[i][j] += (double)a32[i][j];
    __syncthreads();
  }
#pragma unroll
  for (int i = 0; i < 8; ++i) {
    int c = cg * 8 + i;
#pragma unroll
    for (int j = 0; j < 4; ++j) {
      int p = px0 + pg * 4 + j;
      if (p < NPIX) {
        if (c < 18) clsS[((size_t)b * 18 + c) * NPIX + p] = (float)acc[i][j] + clsb[c];
        else if (c < 54) bbp[((size_t)b * 36 + (c - 18)) * NPIX + p] = (float)acc[i][j] + bbb[c - 18];
      }
    }
  }
}

// ---------------- per-anchor: fg score + decode + sort key ----------------
__global__ void k_decode(const float* __restrict__ clsS, const float* __restrict__ bbp,
                         const float* __restrict__ im_info, float* __restrict__ boxes,
                         unsigned long long* __restrict__ keys) {
  int tid = blockIdx.x * 256 + threadIdx.x;
  if (tid >= NBATCH * NA) return;
  int b = tid / NA, n = tid - b * NA;
  int a = n % 9, p = n / 9;
  int h = p / WWW, w = p - h * WWW;
  const float* cb = clsS + (size_t)b * 18 * NPIX;
  float s0 = cb[(size_t)a * NPIX + p];
  float s1 = cb[(size_t)(9 + a) * NPIX + p];
  float mx = fmaxf(s0, s1);
  float e0 = expf(s0 - mx), e1 = expf(s1 - mx);
  float fg = e1 / (e0 + e1);
  const float* bb = bbp + (size_t)b * 36 * NPIX;
  float d0 = bb[(size_t)(a * 4 + 0) * NPIX + p];
  float d1 = bb[(size_t)(a * 4 + 1) * NPIX + p];
  float d2 = bb[(size_t)(a * 4 + 2) * NPIX + p];
  float d3 = bb[(size_t)(a * 4 + 3) * NPIX + p];
  float ax1 = BA[a][0] + w * 16.f, ay1 = BA[a][1] + h * 16.f;
  float ax2 = BA[a][2] + w * 16.f, ay2 = BA[a][3] + h * 16.f;
  float aw = ax2 - ax1 + 1.f, ah = ay2 - ay1 + 1.f;
  float acx = ax1 + 0.5f * aw, acy = ay1 + 0.5f * ah;
  float pcx = d0 * aw + acx, pcy = d1 * ah + acy;
  float pw = expf(d2) * aw, ph = expf(d3) * ah;
  float imh = im_info[b * 3 + 0], imw = im_info[b * 3 + 1];
  float x1 = fminf(fmaxf(pcx - 0.5f * pw, 0.f), imw - 1.f);
  float y1 = fminf(fmaxf(pcy - 0.5f * ph, 0.f), imh - 1.f);
  float x2 = fminf(fmaxf(pcx + 0.5f * pw, 0.f), imw - 1.f);
  float y2 = fminf(fmaxf(pcy + 0.5f * ph, 0.f), imh - 1.f);
  float* bx = boxes + ((size_t)b * NA + n) * 4;
  bx[0] = x1; bx[1] = y1; bx[2] = x2; bx[3] = y2;
  unsigned fb = __float_as_uint(fg);
  keys[((size_t)b << 16) + n] = ((unsigned long long)fb << 32) | (unsigned)(~(unsigned)n);
}

// ---------------- radix-select (48-bit key, 6 passes) + in-kernel compact ----------------
// Plain per-element LDS atomics (round-9 proven). Ballot-aggregation REGRESSED (+43us, round 11).
__global__ __launch_bounds__(1024) void k_rsel_top(const unsigned long long* __restrict__ keys,
                                                   unsigned long long* __restrict__ comp) {
  const int b = blockIdx.x;
  const unsigned long long* kb = keys + ((size_t)b << 16);
  __shared__ int hist[16][256];
  __shared__ int histT[256];
  __shared__ unsigned long long sh_prefix;
  __shared__ unsigned sh_r;
  __shared__ int sh_cnt;
  const int t = threadIdx.x, wid = t >> 6, lane = t & 63;
  if (t == 0) { sh_prefix = 0ull; sh_r = PRE; sh_cnt = 0; }
  __syncthreads();
  for (int p = 5; p >= 0; --p) {
    for (int e = t; e < 4096; e += 1024) ((int*)hist)[e] = 0;
    __syncthreads();
    unsigned long long pref = sh_prefix;
    for (int i = t; i < NA; i += 1024) {
      unsigned long long k = kb[i];
      unsigned long long k48 = ((k >> 16) & 0xFFFFFFFF0000ull) | (k & 0xFFFFull);
      bool m = (p == 5) || ((k48 >> (8 * (p + 1))) == pref);
      if (m) atomicAdd(&hist[wid][(int)((k48 >> (8 * p)) & 255)], 1);
    }
    __syncthreads();
    if (t < 256) { int s = 0; for (int w = 0; w < 16; ++w) s += hist[w][t]; histT[t] = s; }
    __syncthreads();
    if (t == 0) {
      unsigned rr = sh_r; unsigned cum = 0;
      for (int v = 255; v >= 0; --v) {
        cum += (unsigned)histT[v];
        if (cum >= rr) { sh_r = rr - (cum - (unsigned)histT[v]); sh_prefix = (sh_prefix << 8) | (unsigned)v; break; }
      }
    }
    __syncthreads();
  }
  const unsigned long long thr48 = sh_prefix;
  for (int base = 0; base < NA; base += 1024) {
    int i = base + t;
    bool keep = false;
    unsigned long long k = 0ull;
    if (i < NA) {
      k = kb[i];
      unsigned long long k48 = ((k >> 16) & 0xFFFFFFFF0000ull) | (k & 0xFFFFull);
      keep = (k48 >= thr48);
    }
    unsigned long long bal = __ballot(keep);
    if (bal) {
      int leader = __ffsll(bal) - 1;
      int basepos = 0;
      if (lane == leader) basepos = atomicAdd(&sh_cnt, (int)__popcll(bal));
      basepos = __shfl(basepos, leader);
      if (keep) {
        int off = __popcll(bal & ((1ull << lane) - 1ull));
        comp[b * 8192 + basepos + off] = k;
      }
    }
  }
}

// ---------------- one-shot in-LDS bitonic sort of 8192 (descending) + fused gather ----------------
__global__ __launch_bounds__(1024) void k_sort_lds(const unsigned long long* __restrict__ comp,
                                                   const float* __restrict__ boxes,
                                                   float* __restrict__ tbx1, float* __restrict__ tby1,
                                                   float* __restrict__ tbx2, float* __restrict__ tby2,
                                                   float* __restrict__ tba) {
  __shared__ unsigned long long s[8192];
  const int b = blockIdx.x;
  const int t = threadIdx.x;
  const unsigned long long* cb = comp + b * 8192;
  for (int e = t; e < 8192; e += 1024) s[e] = (e < PRE) ? cb[e] : 0ull;
  __syncthreads();
  for (int k = 2; k <= 8192; k <<= 1) {
    for (int j = k >> 1; j >= 1; j >>= 1) {
      for (int q = t; q < 4096; q += 1024) {
        int i = ((q & ~(j - 1)) << 1) | (q & (j - 1));
        int pp = i | j;
        bool up = (i & k) == 0;
        unsigned long long a = s[i], d = s[pp];
        if (up ? (a < d) : (a > d)) { s[i] = d; s[pp] = a; }
      }
      __syncthreads();
    }
  }
  for (int e = t; e < PRE; e += 1024) {
    unsigned long long key = s[e];
    unsigned n = ~(unsigned)(key & 0xFFFFFFFFu);
    const float* bx = boxes + ((size_t)b * NA + n) * 4;
    float x1 = bx[0], y1 = bx[1], x2 = bx[2], y2 = bx[3];
    int o = b * PRE + e;
    tbx1[o] = x1; tby1[o] = y1; tbx2[o] = x2; tby2[o] = y2;
    tba[o] = (x2 - x1 + 1.f) * (y2 - y1 + 1.f);
  }
}

// ---------------- NMS suppression bitmask (j > i) with diagonal skip ----------------
__global__ __launch_bounds__(256) void k_mask(const float* __restrict__ tbx1, const float* __restrict__ tby1,
                                              const float* __restrict__ tbx2, const float* __restrict__ tby2,
                                              const float* __restrict__ tba, unsigned long long* __restrict__ mask) {
  const int b = blockIdx.y;
  const int iblk = blockIdx.x;
  const int i0 = iblk * 64;
  const int t = threadIdx.x;
  __shared__ float jx1[2048], jy1[2048], jx2[2048], jy2[2048], ja[2048];
  __shared__ float ix1[64], iy1[64], ix2[64], iy2[64], ia[64];
  const float* bx1 = tbx1 + b * PRE;
  const float* by1 = tby1 + b * PRE;
  const float* bx2 = tbx2 + b * PRE;
  const float* by2 = tby2 + b * PRE;
  const float* ba2 = tba + b * PRE;
  if (t < 64) {
    int i = i0 + t;
    if (i < PRE) { ix1[t] = bx1[i]; iy1[t] = by1[i]; ix2[t] = bx2[i]; iy2[t] = by2[i]; ia[t] = ba2[i]; }
    else { ix1[t] = 0; iy1[t] = 0; ix2[t] = 0; iy2[t] = 0; ia[t] = 1; }
  }
  for (int c = 0; c < 3; ++c) {
    int j0 = c * 2048;
    if (c * 32 + 31 < iblk) {
      // entire chunk strictly below the diagonal: all words zero (uniform branch, no barriers)
      for (int task = t; task < 64 * 32; task += 256) {
        int il = task & 63, wl = task >> 6;
        int i = i0 + il;
        int wg = c * 32 + wl;
        if (i < PRE && wg < NW) mask[((size_t)(b * PRE + i)) * NW + wg] = 0ull;
      }
      continue;
    }
    for (int e = t; e < 2048; e += 256) {
      int j = j0 + e;
      if (j < PRE) { jx1[e] = bx1[j]; jy1[e] = by1[j]; jx2[e] = bx2[j]; jy2[e] = by2[j]; ja[e] = ba2[j]; }
      else { jx1[e] = 0; jy1[e] = 0; jx2[e] = 0; jy2[e] = 0; ja[e] = 1; }
    }
    __syncthreads();
    for (int task = t; task < 64 * 32; task += 256) {
      int il = task & 63, wl = task >> 6;
      int i = i0 + il;
      int wg = c * 32 + wl;
      if (i >= PRE || wg >= NW) continue;
      if (wg < iblk) { mask[((size_t)(b * PRE + i)) * NW + wg] = 0ull; continue; }
      unsigned long long word = 0ull;
      float X1 = ix1[il], Y1 = iy1[il], X2 = ix2[il], Y2 = iy2[il], A = ia[il];
      for (int l = 0; l < 64; ++l) {
        int j = wg * 64 + l;
        if (j > i && j < PRE) {
          int e = j - j0;
          float iw = fminf(X2, jx2[e]) - fmaxf(X1, jx1[e]) + 1.f;
          float ih = fminf(Y2, jy2[e]) - fmaxf(Y1, jy1[e]) + 1.f;
          if (iw > 0.f && ih > 0.f) {
            float inter = iw * ih;
            float iou = inter / (A + ja[e] - inter);
            if (iou > 0.7f) word |= (1ull << l);
          }
        }
      }
      mask[((size_t)(b * PRE + i)) * NW + wg] = word;
    }
    __syncthreads();
  }
}

// ---------------- serial NMS scan (single wave, register-resident) — proven round-5 version ----------------
__global__ void k_nms(const unsigned long long* __restrict__ mask,
                      const float* __restrict__ tbx1, const float* __restrict__ tby1,
                      const float* __restrict__ tbx2, const float* __restrict__ tby2,
                      float* __restrict__ out) {
  const int b = blockIdx.x;
  const int lane = threadIdx.x;  // 64
  unsigned long long rem0 = 0ull;
  unsigned long long rem1;
  if (64 + lane < NW) rem1 = (64 + lane == NW - 1) ? ~((1ull << (PRE - (NW - 1) * 64)) - 1ull) : 0ull;
  else rem1 = ~0ull;
  int sc = 0;
  for (; sc < POST; ++sc) {
    unsigned long long a0 = ~rem0, a1 = ~rem1;
    unsigned long long bal0 = __ballot(a0 != 0ull);
    int w, l;
    if (bal0) {
      int src = __ffsll(bal0) - 1;
      unsigned long long av = __shfl(a0, src);
      w = src; l = __ffsll(av) - 1;
    } else {
      unsigned long long bal1 = __ballot(a1 != 0ull);
      if (!bal1) break;
      int src = __ffsll(bal1) - 1;
      unsigned long long av = __shfl(a1, src);
      w = 64 + src; l = __ffsll(av) - 1;
    }
    int j = w * 64 + l;
    if (lane < 5) {
      float v;
      if (lane == 0) v = (float)b;
      else if (lane == 1) v = tbx1[b * PRE + j];
      else if (lane == 2) v = tby1[b * PRE + j];
      else if (lane == 3) v = tbx2[b * PRE + j];
      else v = tby2[b * PRE + j];
      out[((size_t)(b * POST + sc)) * 5 + lane] = v;
    }
    const unsigned long long* row = mask + ((size_t)(b * PRE + j)) * NW;
    rem0 |= row[lane];
    if (64 + lane < NW) rem1 |= row[64 + lane];
    if (w < 64) { if (lane == w) rem0 |= (1ull << l); }
    else if (lane == w - 64) rem1 |= (1ull << l);
  }
  for (int r2 = sc; r2 < POST; ++r2)
    if (lane < 5) out[((size_t)(b * POST + r2)) * 5 + lane] = (lane == 0) ? (float)b : 0.f;
}

// ---------------- anchor targets: per-gt max IoU only (block-aggregated atomics) ----------------
__global__ __launch_bounds__(256) void k_gtmax(const float* __restrict__ gt_boxes, const float* __restrict__ im_info,
                                               unsigned* __restrict__ gtmaxU) {
  const int b = blockIdx.y;
  const int n = blockIdx.x * 256 + threadIdx.x;
  const int t = threadIdx.x, lane = t & 63, wv = t >> 6;
  __shared__ float g[NGT][6];
  __shared__ float wmax[4][NGT];
  if (t < NGT) {
    const float* gg = gt_boxes + (b * NGT + t) * 5;
    float x1 = gg[0], y1 = gg[1], x2 = gg[2], y2 = gg[3];
    g[t][0] = x1; g[t][1] = y1; g[t][2] = x2; g[t][3] = y2;
    float gw = x2 - x1 + 1.f, gh = y2 - y1 + 1.f;
    g[t][4] = gw * gh;
    g[t][5] = ((gw == 1.f) && (gh == 1.f)) ? 0.f : 1.f;
  }
  __syncthreads();
  float vj[NGT];
  if (n < NA) {
    int a = n % 9, p = n / 9;
    int h = p / WWW, w = p - h * WWW;
    float ax1 = BA[a][0] + w * 16.f, ay1 = BA[a][1] + h * 16.f;
    float ax2 = BA[a][2] + w * 16.f, ay2 = BA[a][3] + h * 16.f;
    float imh = im_info[b * 3 + 0], imw = im_info[b * 3 + 1];
    bool inside = (ax1 >= 0.f) && (ay1 >= 0.f) && (ax2 < imw) && (ay2 < imh);
    float aw = ax2 - ax1 + 1.f, ah = ay2 - ay1 + 1.f;
    float aa = aw * ah;
#pragma unroll
    for (int j = 0; j < NGT; ++j) {
      float iw = fmaxf(fminf(ax2, g[j][2]) - fmaxf(ax1, g[j][0]) + 1.f, 0.f);
      float ih = fmaxf(fminf(ay2, g[j][3]) - fmaxf(ay1, g[j][1]) + 1.f, 0.f);
      float inter = iw * ih;
      float v = inter / (aa + g[j][4] - inter);
      if (g[j][5] == 0.f) v = 0.f;
      if (!inside) v = -1.f;
      vj[j] = v;
    }
  } else {
#pragma unroll
    for (int j = 0; j < NGT; ++j) vj[j] = -1.f;
  }
#pragma unroll
  for (int j = 0; j < NGT; ++j) {
    float red = vj[j];
    for (int o = 32; o > 0; o >>= 1) red = fmaxf(red, __shfl_xor(red, o));
    if (lane == 0) wmax[wv][j] = red;
  }
  __syncthreads();
  if (t < NGT) {
    float m = fmaxf(fmaxf(wmax[0][t], wmax[1][t]), fmaxf(wmax[2][t], wmax[3][t]));
    if (m > 0.f) atomicMax(&gtmaxU[b * NGT + t], monoF(m));
  }
}

// ---------------- labels + sampling keys (IoU recomputed, bitwise-identical formula) ----------------
__global__ __launch_bounds__(256) void k_labels(const float* __restrict__ gt_boxes,
                                                const unsigned* __restrict__ gtmaxU, const float* __restrict__ im_info,
                                                unsigned kf0, unsigned kf1, unsigned kb0, unsigned kb1,
                                                int* __restrict__ labels, unsigned* __restrict__ ufg,
                                                unsigned* __restrict__ ubg, int* __restrict__ cnts,
                                                int* __restrict__ argm) {
  const int b = blockIdx.y;
  const int n = blockIdx.x * 256 + threadIdx.x;
  const int t = threadIdx.x;
  __shared__ float g[NGT][6];
  __shared__ float gmf[NGT];
  if (t < NGT) {
    const float* gg = gt_boxes + (b * NGT + t) * 5;
    float x1 = gg[0], y1 = gg[1], x2 = gg[2], y2 = gg[3];
    g[t][0] = x1; g[t][1] = y1; g[t][2] = x2; g[t][3] = y2;
    float gw = x2 - x1 + 1.f, gh = y2 - y1 + 1.f;
    g[t][4] = gw * gh;
    g[t][5] = ((gw == 1.f) && (gh == 1.f)) ? 0.f : 1.f;
    float gm = unmonoF(gtmaxU[b * NGT + t]);
    gmf[t] = (gm <= 0.f) ? 1e-5f : gm;
  }
  __syncthreads();
  int label = -1;
  if (n < NA) {
    int a = n % 9, p = n / 9;
    int h = p / WWW, w = p - h * WWW;
    float ax1 = BA[a][0] + w * 16.f, ay1 = BA[a][1] + h * 16.f;
    float ax2 = BA[a][2] + w * 16.f, ay2 = BA[a][3] + h * 16.f;
    float imh = im_info[b * 3 + 0], imw = im_info[b * 3 + 1];
    bool inside = (ax1 >= 0.f) && (ay1 >= 0.f) && (ax2 < imw) && (ay2 < imh);
    float aw = ax2 - ax1 + 1.f, ah = ay2 - ay1 + 1.f;
    float aa = aw * ah;
    float best = -2.f;
    int barg = 0;
    bool keep = false;
#pragma unroll
    for (int j = 0; j < NGT; ++j) {
      float iw = fmaxf(fminf(ax2, g[j][2]) - fmaxf(ax1, g[j][0]) + 1.f, 0.f);
      float ih = fmaxf(fminf(ay2, g[j][3]) - fmaxf(ay1, g[j][1]) + 1.f, 0.f);
      float inter = iw * ih;
      float v = inter / (aa + g[j][4] - inter);
      if (g[j][5] == 0.f) v = 0.f;
      if (!inside) v = -1.f;
      keep = keep || (v == gmf[j]);
      if (v > best) { best = v; barg = j; }
    }
    float mo = best;
    if (mo < 0.3f) label = 0;
    if (keep) label = 1;
    if (mo >= 0.7f) label = 1;
    if (!inside) label = -1;
    labels[b * NA + n] = label;
    argm[b * NA + n] = barg;
    unsigned pp = (unsigned)(b * NA + n);
    ufg[b * NA + n] = (label == 1) ? tf_u23(kf0, kf1, pp) : 0x00FFFFFFu;
    ubg[b * NA + n] = (label == 0) ? tf_u23(kb0, kb1, pp) : 0x00FFFFFFu;
  }
  unsigned long long bf = __ballot(label == 1);
  unsigned long long bb = __ballot(label == 0);
  if ((threadIdx.x & 63) == 0) {
    atomicAdd(&cnts[b], (int)__popcll(bf));
    atomicAdd(&cnts[4 + b], (int)__popcll(bb));
  }
}

// ---------------- radix rank-k selection for fg/bg sampling (stable, idx tie-break) ----------------
__global__ __launch_bounds__(1024) void k_rsel_samp(const unsigned* __restrict__ ufg, const unsigned* __restrict__ ubg,
                                                    const int* __restrict__ cnts, unsigned* __restrict__ selp,
                                                    float* __restrict__ nexf) {
  const int blk = blockIdx.x;  // 0..7
  const int b = blk >> 1, cls = blk & 1;
  const unsigned* u = (cls == 0 ? ufg : ubg) + (size_t)b * NA;
  const int fcnt = cnts[b], bcnt = cnts[4 + b];
  const int kk = (cls == 0) ? 128 : (256 - (fcnt < 128 ? fcnt : 128));
  const int cnt = (cls == 0) ? fcnt : bcnt;
  const int t = threadIdx.x, wid = t >> 6;
  __shared__ int hist[16][256];
  __shared__ int histT[256];
  __shared__ unsigned long long sh_prefix;
  __shared__ unsigned sh_r;
  if (t == 0) {
    if (cls == 1) {
      int fk = fcnt < 128 ? fcnt : 128;
      int bk2 = bcnt < kk ? bcnt : kk;
      nexf[b] = (float)(fk + bk2);
    }
    sh_prefix = 0ull; sh_r = (unsigned)kk;
  }
  __syncthreads();
  if (kk > cnt) {
    if (t == 0) { selp[blk * 2] = 0x00FFFFFFu; selp[blk * 2 + 1] = 0x1FFFFu; }
    return;
  }
  for (int p = 4; p >= 0; --p) {
    for (int e = t; e < 4096; e += 1024) ((int*)hist)[e] = 0;
    __syncthreads();
    unsigned long long pref = sh_prefix;
    for (int i = t; i < NA; i += 1024) {
      unsigned uv = u[i];
      if (uv == 0x00FFFFFFu) continue;
      unsigned long long k = ((unsigned long long)uv << 17) | (unsigned)i;
      if ((k >> (8 * (p + 1))) == pref)
        atomicAdd(&hist[wid][(int)((k >> (8 * p)) & 255)], 1);
    }
    __syncthreads();
    if (t < 256) { int s = 0; for (int w = 0; w < 16; ++w) s += hist[w][t]; histT[t] = s; }
    __syncthreads();
    if (t == 0) {
      unsigned rr = sh_r; unsigned cum = 0;
      for (int v = 0; v < 256; ++v) {
        cum += (unsigned)histT[v];
        if (cum >= rr) { sh_r = rr - (cum - (unsigned)histT[v]); sh_prefix = (sh_prefix << 8) | (unsigned)v; break; }
      }
    }
    __syncthreads();
  }
  if (t == 0) {
    selp[blk * 2] = (unsigned)(sh_prefix >> 17);
    selp[blk * 2 + 1] = (unsigned)(sh_prefix & 0x1FFFF);
  }
}

// ---------------- losses ----------------
__global__ __launch_bounds__(256) void k_loss(const float* __restrict__ clsS, const float* __restrict__ bbp,
                                              const float* __restrict__ gt_boxes, const int* __restrict__ labels,
                                              const unsigned* __restrict__ ufg, const unsigned* __restrict__ ubg,
                                              const unsigned* __restrict__ selp, const int* __restrict__ argm,
                                              float* __restrict__ accums) {
  const int b = blockIdx.y;
  const int n = blockIdx.x * 256 + threadIdx.x;
  float nll = 0.f, mcnt = 0.f, lbsum = 0.f;
  if (n < NA) {
    int label = labels[b * NA + n];
    int fin = -1;
    if (label == 1) {
      unsigned uu = ufg[b * NA + n];
      unsigned thr = selp[(b * 2 + 0) * 2], ithr = selp[(b * 2 + 0) * 2 + 1];
      if (uu < thr || (uu == thr && (unsigned)n <= ithr)) fin = 1;
    } else if (label == 0) {
      unsigned uu = ubg[b * NA + n];
      unsigned thr = selp[(b * 2 + 1) * 2], ithr = selp[(b * 2 + 1) * 2 + 1];
      if (uu < thr || (uu == thr && (unsigned)n <= ithr)) fin = 0;
    }
    if (fin >= 0) {
      int a = n % 9, p = n / 9;
      float s0 = clsS[((size_t)b * 18 + a) * NPIX + p];
      float s1 = clsS[((size_t)b * 18 + 9 + a) * NPIX + p];
      float mx = fmaxf(s0, s1);
      float lse = mx + logf(expf(s0 - mx) + expf(s1 - mx));
      nll = lse - (fin == 1 ? s1 : s0);
      mcnt = 1.f;
      if (fin == 1) {
        int h = p / WWW, w = p - h * WWW;
        float ax1 = BA[a][0] + w * 16.f, ay1 = BA[a][1] + h * 16.f;
        float ax2 = BA[a][2] + w * 16.f, ay2 = BA[a][3] + h * 16.f;
        float ew = ax2 - ax1 + 1.f, eh = ay2 - ay1 + 1.f;
        float ecx = ax1 + 0.5f * ew, ecy = ay1 + 0.5f * eh;
        int ag = argm[b * NA + n];
        const float* gg = gt_boxes + (b * NGT + ag) * 5;
        float gw = gg[2] - gg[0] + 1.f, gh = gg[3] - gg[1] + 1.f;
        float gcx = gg[0] + 0.5f * gw, gcy = gg[1] + 0.5f * gh;
        float tt[4];
        tt[0] = (gcx - ecx) / ew;
        tt[1] = (gcy - ecy) / eh;
        tt[2] = logf(gw / ew);
        tt[3] = logf(gh / eh);
#pragma unroll
        for (int dd = 0; dd < 4; ++dd) {
          float pd = bbp[((size_t)b * 36 + (a * 4 + dd)) * NPIX + p];
          float diff = pd - tt[dd];
          float ad = fabsf(diff);
          lbsum += (ad < 1.f / 9.f) ? 4.5f * diff * diff : (ad - 0.5f / 9.f);
        }
      }
    }
  }
  for (int o = 32; o > 0; o >>= 1) {
    nll += __shfl_down(nll, o);
    mcnt += __shfl_down(mcnt, o);
    lbsum += __shfl_down(lbsum, o);
  }
  __shared__ float p0[4], p1[4], p2[4];
  int wid = threadIdx.x >> 6;
  if ((threadIdx.x & 63) == 0) { p0[wid] = nll; p1[wid] = mcnt; p2[wid] = lbsum; }
  __syncthreads();
  if (threadIdx.x == 0) {
    float aS = 0, bS = 0, cS = 0;
    for (int q = 0; q < 4; ++q) { aS += p0[q]; bS += p1[q]; cS += p2[q]; }
    atomicAdd(&accums[0], aS);
    atomicAdd(&accums[1], bS);
    atomicAdd(&accums[2 + b], cS);
  }
}

__global__ void k_final(const float* __restrict__ accums, const float* __restrict__ nexf, float* __restrict__ out) {
  if (threadIdx.x == 0 && blockIdx.x == 0) {
    out[6000] = accums[0] / accums[1];
    float lb = 0.f;
    for (int b = 0; b < NBATCH; ++b) lb += accums[2 + b] / nexf[b];
    out[6001] = lb * 0.25f;
  }
}

// ---------------- host ----------------
extern "C" void kernel_launch(void* const* d_in, const int* in_sizes, int n_in,
                              void* d_out, int out_size, void* d_ws, size_t ws_size,
                              hipStream_t stream) {
  (void)in_sizes; (void)n_in; (void)out_size; (void)ws_size;
  const float* base_feat = (const float*)d_in[0];
  const float* im_info   = (const float*)d_in[1];
  const float* gt_boxes  = (const float*)d_in[2];
  const float* conv_w    = (const float*)d_in[4];
  const float* conv_b    = (const float*)d_in[5];
  const float* cls_w     = (const float*)d_in[6];
  const float* cls_b     = (const float*)d_in[7];
  const float* bbox_w    = (const float*)d_in[8];
  const float* bbox_b    = (const float*)d_in[9];
  float* out = (float*)d_out;

  char* wp = (char*)d_ws;
  auto carve = [&](size_t bytes) -> void* {
    void* r = (void*)wp;
    wp += (bytes + 255) & ~(size_t)255;
    return r;
  };
  // region A: live across both phases
  float* x     = (float*)carve((size_t)NBATCH * CIN * NPIX * 4);
  float* clsS  = (float*)carve((size_t)NBATCH * 18 * NPIX * 4);
  float* bbp   = (float*)carve((size_t)NBATCH * 36 * NPIX * 4);
  unsigned short* WT0 = (unsigned short*)carve((size_t)9 * 64 * 512 * 8 * 2);
  unsigned short* WT1 = (unsigned short*)carve((size_t)9 * 64 * 512 * 8 * 2);
  unsigned short* WT2 = (unsigned short*)carve((size_t)9 * 64 * 512 * 8 * 2);
  float* wt1   = (float*)carve((size_t)CIN * 64 * 4);
  unsigned* gtmaxU = (unsigned*)carve(NBATCH * NGT * 4);
  int* cnts    = (int*)carve(8 * 4);
  unsigned* selp = (unsigned*)carve(16 * 4);
  float* nexf  = (float*)carve(4 * 4);
  float* accums = (float*)carve(8 * 4);

  // region B: X splits (conv3 phase) overlaid with post-conv buffers
  char* overlay = wp;
  unsigned short* XT0 = (unsigned short*)overlay;
  unsigned short* XT1 = XT0 + (size_t)NBATCH * XTB;
  unsigned short* XT2 = XT1 + (size_t)NBATCH * XTB;
  char* wp2 = overlay;
  auto carve2 = [&](size_t bytes) -> void* {
    void* r = (void*)wp2;
    wp2 += (bytes + 255) & ~(size_t)255;
    return r;
  };
  float* boxes = (float*)carve2((size_t)NBATCH * NA * 4 * 4);
  unsigned long long* keys = (unsigned long long*)carve2((size_t)NBATCH * 65536 * 8);
  float* tbx1 = (float*)carve2((size_t)NBATCH * PRE * 4);
  float* tby1 = (float*)carve2((size_t)NBATCH * PRE * 4);
  float* tbx2 = (float*)carve2((size_t)NBATCH * PRE * 4);
  float* tby2 = (float*)carve2((size_t)NBATCH * PRE * 4);
  float* tba  = (float*)carve2((size_t)NBATCH * PRE * 4);
  unsigned long long* mask = (unsigned long long*)carve2((size_t)NBATCH * PRE * NW * 8);
  int* argm    = (int*)carve2((size_t)NBATCH * NA * 4);
  int* labels  = (int*)carve2((size_t)NBATCH * NA * 4);
  unsigned* ufg = (unsigned*)carve2((size_t)NBATCH * NA * 4);
  unsigned* ubg = (unsigned*)carve2((size_t)NBATCH * NA * 4);
  unsigned long long* comp = (unsigned long long*)carve2((size_t)NBATCH * 8192 * 8);

  // rbg key = threefry_fold_in(key(42), 1)
  unsigned kb0 = 0u, kb1 = 1u;
  tf2x32(0u, 42u, kb0, kb1);

  k_split_w<<<dim3((9 * 64 * 512 * 8) / 256), dim3(256), 0, stream>>>(conv_w, WT0, WT1, WT2, gtmaxU, cnts, accums);
  k_tr_w1<<<dim3((CIN * 64) / 256), dim3(256), 0, stream>>>(cls_w, bbox_w, wt1);
  k_split_x<<<dim3(64, NBATCH), dim3(256), 0, stream>>>(base_feat, XT0, XT1, XT2);
  k_conv3<<<dim3(1024), dim3(256), 0, stream>>>(XT0, XT1, XT2, WT0, WT1, WT2, conv_b, x);
  k_conv1<<<dim3(30, 4), dim3(256), 0, stream>>>(x, wt1, cls_b, bbox_b, clsS, bbp);
  k_decode<<<dim3((NBATCH * NA + 255) / 256), dim3(256), 0, stream>>>(clsS, bbp, im_info, boxes, keys);
  k_rsel_top<<<dim3(NBATCH), dim3(1024), 0, stream>>>(keys, comp);
  k_sort_lds<<<dim3(NBATCH), dim3(1024), 0, stream>>>(comp, boxes, tbx1, tby1, tbx2, tby2, tba);
  k_mask<<<dim3(NW, NBATCH), dim3(256), 0, stream>>>(tbx1, tby1, tbx2, tby2, tba, mask);
  k_nms<<<dim3(NBATCH), dim3(64), 0, stream>>>(mask, tbx1, tby1, tbx2, tby2, out);
  k_gtmax<<<dim3((NA + 255) / 256, NBATCH), dim3(256), 0, stream>>>(gt_boxes, im_info, gtmaxU);
  k_labels<<<dim3((NA + 255) / 256, NBATCH), dim3(256), 0, stream>>>(gt_boxes, gtmaxU, im_info,
                                                                     0u, 42u, kb0, kb1, labels, ufg, ubg, cnts, argm);
  k_rsel_samp<<<dim3(8), dim3(1024), 0, stream>>>(ufg, ubg, cnts, selp, nexf);
  k_loss<<<dim3((NA + 255) / 256, NBATCH), dim3(256), 0, stream>>>(clsS, bbp, gt_boxes, labels, ufg, ubg, selp, argm, accums);
  k_final<<<dim3(1), dim3(1), 0, stream>>>(accums, nexf, out);
}

// Round 15
// 1420.355 us; speedup vs baseline: 1.0192x; 1.0192x over previous
//
#include <hip/hip_runtime.h>
#include <stdint.h>

#define HHH 50
#define WWW 76
#define NPIX 3800
#define NA 34200
#define PRE 6000
#define POST 300
#define NW 94            // ceil(6000/64)
#define CIN 512
#define COUT 512
#define NBATCH 4
#define NGT 20
#define TFHALF 68400u    // (4*34200)/2
#define XTB 2252800      // 275 pg * 64 cg * 16 po * 8 cl (elems per batch per split)

typedef __bf16 bf16x8 __attribute__((ext_vector_type(8)));
typedef float f32x4 __attribute__((ext_vector_type(4)));
typedef unsigned int u32x4v __attribute__((ext_vector_type(4)));

__device__ static inline f32x4 MFMA16(bf16x8 a, bf16x8 b, f32x4 c) {
  return __builtin_amdgcn_mfma_f32_16x16x32_bf16(a, b, c, 0, 0, 0);
}
__device__ static inline bf16x8 LD8(const unsigned short* p) {
  return __builtin_bit_cast(bf16x8, *(const u32x4v*)p);
}

// ---------------- threefry2x32 (exact JAX lowering) ----------------
__host__ __device__ static inline void tf2x32(unsigned k0, unsigned k1, unsigned& x0, unsigned& x1) {
  unsigned k2 = k0 ^ k1 ^ 0x1BD11BDAu;
#define TFR(r) do { x0 += x1; x1 = (x1 << (r)) | (x1 >> (32 - (r))); x1 ^= x0; } while (0)
  x0 += k0; x1 += k1;
  TFR(13); TFR(15); TFR(26); TFR(6);
  x0 += k1; x1 += k2 + 1u;
  TFR(17); TFR(29); TFR(16); TFR(24);
  x0 += k2; x1 += k0 + 2u;
  TFR(13); TFR(15); TFR(26); TFR(6);
  x0 += k0; x1 += k1 + 3u;
  TFR(17); TFR(29); TFR(16); TFR(24);
  x0 += k1; x1 += k2 + 4u;
  TFR(13); TFR(15); TFR(26); TFR(6);
  x0 += k2; x1 += k0 + 5u;
#undef TFR
}

__device__ static inline unsigned tf_u23(unsigned k0, unsigned k1, unsigned p) {
  unsigned x0, x1;
  if (p < TFHALF) { x0 = p; x1 = p + TFHALF; tf2x32(k0, k1, x0, x1); return x0 >> 9; }
  x0 = p - TFHALF; x1 = p; tf2x32(k0, k1, x0, x1); return x1 >> 9;
}

// base anchors (scales 8/16/32 x ratios .5/1/2, ratio-major)
__device__ const float BA[9][4] = {
  {-84.f, -40.f,  99.f,  55.f}, {-176.f, -88.f, 191.f, 103.f}, {-360.f, -184.f, 375.f, 199.f},
  {-56.f, -56.f,  71.f,  71.f}, {-120.f, -120.f, 135.f, 135.f}, {-248.f, -248.f, 263.f, 263.f},
  {-36.f, -80.f,  51.f,  95.f}, {-80.f, -168.f,  95.f, 183.f}, {-168.f, -344.f, 183.f, 359.f}
};

__device__ static inline unsigned monoF(float f) {
  int b = __float_as_int(f);
  unsigned u = (unsigned)b;
  return (b < 0) ? ~u : (u | 0x80000000u);
}
__device__ static inline float unmonoF(unsigned u) {
  unsigned b = (u & 0x80000000u) ? (u ^ 0x80000000u) : ~u;
  return __int_as_float((int)b);
}

// exact 3-way bf16 split: v == h + m + l
__device__ static inline void split3(float v, unsigned short& h, unsigned short& m, unsigned short& l) {
  __bf16 b0 = (__bf16)v;  float f0 = (float)b0;
  float r = v - f0;       __bf16 b1 = (__bf16)r;  float f1 = (float)b1;
  float r2 = r - f1;      __bf16 b2 = (__bf16)r2;
  h = __builtin_bit_cast(unsigned short, b0);
  m = __builtin_bit_cast(unsigned short, b1);
  l = __builtin_bit_cast(unsigned short, b2);
}

// ---------------- X split into padded fragment-linear layout (round-13 proven) ----------------
__global__ void k_split_x(const float* __restrict__ feat, unsigned short* __restrict__ x0,
                          unsigned short* __restrict__ x1, unsigned short* __restrict__ x2) {
  int tid = blockIdx.x * 256 + threadIdx.x;
  if (tid >= NBATCH * XTB) return;
  int b = tid / XTB;
  int rem = tid - b * XTB;
  int pg = rem >> 13;
  int r2 = rem & 8191;
  int cg = r2 >> 7;
  int po = (r2 >> 3) & 15;
  int cl = r2 & 7;
  int ci = cg * 8 + cl;
  int px = pg * 16 + po;
  int hq = px / 80, wq = px - hq * 80;
  float v = 0.f;
  if (hq >= 2 && hq < 52 && wq >= 1 && wq < 77)
    v = feat[((size_t)(b * 512 + ci)) * NPIX + (hq - 2) * 76 + (wq - 1)];
  unsigned short h, m, l;
  split3(v, h, m, l);
  x0[tid] = h; x1[tid] = m; x2[tid] = l;
}

// ---------------- W split (+ absorbed init): WT_s[tap][cg 64][co 512][cl 8] bf16 ----------------
__global__ void k_split_w(const float* __restrict__ cw, unsigned short* __restrict__ w0,
                          unsigned short* __restrict__ w1, unsigned short* __restrict__ w2,
                          unsigned* __restrict__ gtmaxU, int* __restrict__ cnts, float* __restrict__ accums) {
  int tid = blockIdx.x * 256 + threadIdx.x;
  if (blockIdx.x == 0) {
    int t = threadIdx.x;
    if (t < NBATCH * NGT) gtmaxU[t] = 0x407FFFFFu;  // mono(-1.0f)
    if (t < 8) cnts[t] = 0;
    if (t < 8) accums[t] = 0.f;
  }
  if (tid >= 9 * 64 * 512 * 8) return;
  int cl = tid & 7;
  int co = (tid >> 3) & 511;
  int cg = (tid >> 12) & 63;
  int tap = tid >> 18;
  int ci = cg * 8 + cl;
  float v = cw[((size_t)co * 512 + ci) * 9 + tap];
  unsigned short h, m, l;
  split3(v, h, m, l);
  w0[tid] = h; w1[tid] = m; w2[tid] = l;
}

__global__ void k_tr_w1(const float* __restrict__ clsw, const float* __restrict__ bbw, float* __restrict__ wt1) {
  int tid = blockIdx.x * 256 + threadIdx.x;
  if (tid >= CIN * 64) return;
  int c = tid & 63, ci = tid >> 6;
  float v = 0.f;
  if (c < 18) v = clsw[c * 512 + ci];
  else if (c < 54) v = bbw[(c - 18) * 512 + ci];
  wt1[tid] = v;  // [ci][64]
}

// ---------------- conv 3x3 + ReLU via 3-split bf16 MFMA — FROZEN round-9 form ----------------
// f64 masters folded every 2 kg. ERRATA r6: (256,3) reg-cap -> spill (+373us).
// ERRATA r12: f32 fold-every-kg -> dependency join per kg, 517->722us. Do not restructure.
__global__ __launch_bounds__(256, 2) void k_conv3(
    const unsigned short* __restrict__ XT0, const unsigned short* __restrict__ XT1,
    const unsigned short* __restrict__ XT2,
    const unsigned short* __restrict__ WT0, const unsigned short* __restrict__ WT1,
    const unsigned short* __restrict__ WT2,
    const float* __restrict__ bias, float* __restrict__ out) {
  const int d = blockIdx.x;
  const int copair = (d >> 1) & 3, half = d & 1, g = d >> 3;
  const int cob = copair * 2 + (g & 1);
  const int pxb = half * 64 + (g >> 1);
  const int pxp = pxb & 31, b = pxb >> 5;
  const int co0 = cob * 64;
  const int px0 = 160 + pxp * 128;
  const int t = threadIdx.x, l = t & 63, wv = t >> 6;
  const int wr = wv >> 1, wc = wv & 1;
  const int l15 = l & 15, lq = l >> 4;
  f32x4 cmain[2][4], ccorr[2][4];
  double accd[2][4][4];
#pragma unroll
  for (int c = 0; c < 2; ++c)
#pragma unroll
    for (int p = 0; p < 4; ++p) {
      cmain[c][p] = (f32x4)(0.f); ccorr[c][p] = (f32x4)(0.f);
#pragma unroll
      for (int r = 0; r < 4; ++r) accd[c][p][r] = 0.0;
    }
  const unsigned short* xt0 = XT0 + (size_t)b * XTB;
  const unsigned short* xt1 = XT1 + (size_t)b * XTB;
  const unsigned short* xt2 = XT2 + (size_t)b * XTB;
  const int coA = wr * 32 + l15;
  const int OFFT[9] = {-81, -80, -79, -1, 0, 1, 79, 80, 81};
  const int pxw = px0 + wc * 64 + l15;

  for (int kg = 0; kg < 16; ++kg) {
    const int cgl = kg * 4 + lq;
    const int cglo = cgl * 128;
    const size_t aro = ((size_t)cgl * 512 + co0 + coA) * 8;
#pragma unroll
    for (int tap = 0; tap < 9; ++tap) {
      const size_t ao = aro + (size_t)tap * (64 * 512 * 8);
      bf16x8 A0[2], A1[2], A2[2];
      A0[0] = LD8(WT0 + ao); A0[1] = LD8(WT0 + ao + 128);
      A1[0] = LD8(WT1 + ao); A1[1] = LD8(WT1 + ao + 128);
      A2[0] = LD8(WT2 + ao); A2[1] = LD8(WT2 + ao + 128);
      const int pxbase = pxw + OFFT[tap];
      const size_t eob = (size_t)((pxbase >> 4) * 8192 + (pxbase & 15) * 8 + cglo);
#pragma unroll
      for (int p = 0; p < 4; ++p) {
        const size_t eo = eob + (size_t)p * 8192;
        bf16x8 B0 = LD8(xt0 + eo);
        bf16x8 B1 = LD8(xt1 + eo);
        bf16x8 B2 = LD8(xt2 + eo);
#pragma unroll
        for (int c = 0; c < 2; ++c) {
          cmain[c][p] = MFMA16(A0[c], B0, cmain[c][p]);
          ccorr[c][p] = MFMA16(A2[c], B0, ccorr[c][p]);
          ccorr[c][p] = MFMA16(A0[c], B2, ccorr[c][p]);
          ccorr[c][p] = MFMA16(A1[c], B1, ccorr[c][p]);
          ccorr[c][p] = MFMA16(A1[c], B0, ccorr[c][p]);
          ccorr[c][p] = MFMA16(A0[c], B1, ccorr[c][p]);
        }
      }
    }
    if (kg & 1) {  // fold K=64ci x 9tap window into f64 masters
#pragma unroll
      for (int c = 0; c < 2; ++c)
#pragma unroll
        for (int p = 0; p < 4; ++p) {
#pragma unroll
          for (int r = 0; r < 4; ++r) accd[c][p][r] += (double)cmain[c][p][r];
          cmain[c][p] = (f32x4)(0.f);
        }
    }
  }
  const size_t outb = ((size_t)b * 512 + co0) * NPIX;
#pragma unroll
  for (int c = 0; c < 2; ++c)
#pragma unroll
    for (int p = 0; p < 4; ++p)
#pragma unroll
      for (int r = 0; r < 4; ++r) {
        int coL = wr * 32 + c * 16 + lq * 4 + r;
        int px = px0 + wc * 64 + p * 16 + l15;
        int hq = px / 80, wq = px - hq * 80;
        if (hq >= 2 && hq < 52 && wq >= 1 && wq < 77) {
          float v = (float)(accd[c][p][r] + (double)ccorr[c][p][r]) + bias[co0 + coL];
          out[outb + (size_t)coL * NPIX + (hq - 2) * 76 + (wq - 1)] = fmaxf(v, 0.f);
        }
      }
}

// ---------------- 1x1 convs: cls(18) + bbox(36) fused, f64 chunk accumulation ----------------
__global__ __launch_bounds__(256) void k_conv1(const float* __restrict__ x, const float* __restrict__ wt1,
                                               const float* __restrict__ clsb, const float* __restrict__ bbb,
                                               float* __restrict__ clsS, float* __restrict__ bbp) {
  const int b = blockIdx.y;
  const int px0 = blockIdx.x * 128;
  const int t = threadIdx.x;
  const int cg = t & 7, pg = t >> 3;
  __shared__ float xs[16][128];
  __shared__ float ws[16][72];
  double acc[8][4];
#pragma unroll
  for (int i = 0; i < 8; ++i)
#pragma unroll
    for (int j = 0; j < 4; ++j) acc[i][j] = 0.0;
  const float* xb = x + (size_t)b * CIN * NPIX;
  for (int cc = 0; cc < CIN; cc += 16) {
#pragma unroll
    for (int e0 = 0; e0 < 8; ++e0) {
      int e = t + e0 * 256;
      int r = e >> 7, c = e & 127;
      int p = px0 + c;
      xs[r][c] = (p < NPIX) ? xb[(size_t)(cc + r) * NPIX + p] : 0.f;
    }
#pragma unroll
    for (int e0 = 0; e0 < 4; ++e0) {
      int e = t + e0 * 256;
      int r = e >> 6, c = e & 63;
      ws[r][c + ((c >> 5) << 2)] = wt1[(cc + r) * 64 + c];
    }
    __syncthreads();
    const int wcol = (cg << 3) + ((cg >> 2) << 2);
    const int xcol = pg << 2;
    float a32[8][4];
#pragma unroll
    for (int i = 0; i < 8; ++i)
#pragma unroll
      for (int j = 0; j < 4; ++j) a32[i][j] = 0.f;
#pragma unroll
    for (int k = 0; k < 16; ++k) {
      const float4 w0 = *(const float4*)&ws[k][wcol];
      const float4 w1 = *(const float4*)&ws[k][wcol + 4];
      const float4 xa = *(const float4*)&xs[k][xcol];
      const float wv[8] = {w0.x, w0.y, w0.z, w0.w, w1.x, w1.y, w1.z, w1.w};
      const float xv[4] = {xa.x, xa.y, xa.z, xa.w};
#pragma unroll
      for (int i = 0; i < 8; ++i)
#pragma unroll
        for (int j = 0; j < 4; ++j)
          a32[i][j] = fmaf(wv[i], xv[j], a32[i][j]);
    }
#pragma unroll
    for (int i = 0; i < 8; ++i)
#pragma unroll
      for (int j = 0; j < 4; ++j) acc[i][j] += (double)a32[i][j];
    __syncthreads();
  }
#pragma unroll
  for (int i = 0; i < 8; ++i) {
    int c = cg * 8 + i;
#pragma unroll
    for (int j = 0; j < 4; ++j) {
      int p = px0 + pg * 4 + j;
      if (p < NPIX) {
        if (c < 18) clsS[((size_t)b * 18 + c) * NPIX + p] = (float)acc[i][j] + clsb[c];
        else if (c < 54) bbp[((size_t)b * 36 + (c - 18)) * NPIX + p] = (float)acc[i][j] + bbb[c - 18];
      }
    }
  }
}

// ---------------- per-anchor: fg score + decode + sort key ----------------
__global__ void k_decode(const float* __restrict__ clsS, const float* __restrict__ bbp,
                         const float* __restrict__ im_info, float* __restrict__ boxes,
                         unsigned long long* __restrict__ keys) {
  int tid = blockIdx.x * 256 + threadIdx.x;
  if (tid >= NBATCH * NA) return;
  int b = tid / NA, n = tid - b * NA;
  int a = n % 9, p = n / 9;
  int h = p / WWW, w = p - h * WWW;
  const float* cb = clsS + (size_t)b * 18 * NPIX;
  float s0 = cb[(size_t)a * NPIX + p];
  float s1 = cb[(size_t)(9 + a) * NPIX + p];
  float mx = fmaxf(s0, s1);
  float e0 = expf(s0 - mx), e1 = expf(s1 - mx);
  float fg = e1 / (e0 + e1);
  const float* bb = bbp + (size_t)b * 36 * NPIX;
  float d0 = bb[(size_t)(a * 4 + 0) * NPIX + p];
  float d1 = bb[(size_t)(a * 4 + 1) * NPIX + p];
  float d2 = bb[(size_t)(a * 4 + 2) * NPIX + p];
  float d3 = bb[(size_t)(a * 4 + 3) * NPIX + p];
  float ax1 = BA[a][0] + w * 16.f, ay1 = BA[a][1] + h * 16.f;
  float ax2 = BA[a][2] + w * 16.f, ay2 = BA[a][3] + h * 16.f;
  float aw = ax2 - ax1 + 1.f, ah = ay2 - ay1 + 1.f;
  float acx = ax1 + 0.5f * aw, acy = ay1 + 0.5f * ah;
  float pcx = d0 * aw + acx, pcy = d1 * ah + acy;
  float pw = expf(d2) * aw, ph = expf(d3) * ah;
  float imh = im_info[b * 3 + 0], imw = im_info[b * 3 + 1];
  float x1 = fminf(fmaxf(pcx - 0.5f * pw, 0.f), imw - 1.f);
  float y1 = fminf(fmaxf(pcy - 0.5f * ph, 0.f), imh - 1.f);
  float x2 = fminf(fmaxf(pcx + 0.5f * pw, 0.f), imw - 1.f);
  float y2 = fminf(fmaxf(pcy + 0.5f * ph, 0.f), imh - 1.f);
  float* bx = boxes + ((size_t)b * NA + n) * 4;
  bx[0] = x1; bx[1] = y1; bx[2] = x2; bx[3] = y2;
  unsigned fb = __float_as_uint(fg);
  keys[((size_t)b << 16) + n] = ((unsigned long long)fb << 32) | (unsigned)(~(unsigned)n);
}

// ---------------- fused: radix-select (48-bit, 6 passes) + LDS compact + in-LDS sort + gather ----------------
// Radix histogram uses plain per-element LDS atomics (round-9 proven; ballot-agg regressed r11).
// Compacted keys go straight to LDS (no global comp round-trip), sorted, then gathered.
__global__ __launch_bounds__(1024) void k_rsel_sort(const unsigned long long* __restrict__ keys,
                                                    const float* __restrict__ boxes,
                                                    float* __restrict__ tbx1, float* __restrict__ tby1,
                                                    float* __restrict__ tbx2, float* __restrict__ tby2,
                                                    float* __restrict__ tba) {
  const int b = blockIdx.x;
  const unsigned long long* kb = keys + ((size_t)b << 16);
  __shared__ unsigned long long s[8192];       // compact + sort buffer
  __shared__ int hist[16][256];
  __shared__ int histT[256];
  __shared__ unsigned long long sh_prefix;
  __shared__ unsigned sh_r;
  __shared__ int sh_cnt;
  const int t = threadIdx.x, wid = t >> 6, lane = t & 63;
  if (t == 0) { sh_prefix = 0ull; sh_r = PRE; sh_cnt = 0; }
  for (int e = t; e < 8192; e += 1024) s[e] = 0ull;
  __syncthreads();
  // phase 1: radix select threshold
  for (int p = 5; p >= 0; --p) {
    for (int e = t; e < 4096; e += 1024) ((int*)hist)[e] = 0;
    __syncthreads();
    unsigned long long pref = sh_prefix;
    for (int i = t; i < NA; i += 1024) {
      unsigned long long k = kb[i];
      unsigned long long k48 = ((k >> 16) & 0xFFFFFFFF0000ull) | (k & 0xFFFFull);
      bool m = (p == 5) || ((k48 >> (8 * (p + 1))) == pref);
      if (m) atomicAdd(&hist[wid][(int)((k48 >> (8 * p)) & 255)], 1);
    }
    __syncthreads();
    if (t < 256) { int sS = 0; for (int w = 0; w < 16; ++w) sS += hist[w][t]; histT[t] = sS; }
    __syncthreads();
    if (t == 0) {
      unsigned rr = sh_r; unsigned cum = 0;
      for (int v = 255; v >= 0; --v) {
        cum += (unsigned)histT[v];
        if (cum >= rr) { sh_r = rr - (cum - (unsigned)histT[v]); sh_prefix = (sh_prefix << 8) | (unsigned)v; break; }
      }
    }
    __syncthreads();
  }
  const unsigned long long thr48 = sh_prefix;
  // phase 2: compact exactly PRE keys (>= thr48) into LDS
  for (int base = 0; base < NA; base += 1024) {
    int i = base + t;
    bool keep = false;
    unsigned long long k = 0ull;
    if (i < NA) {
      k = kb[i];
      unsigned long long k48 = ((k >> 16) & 0xFFFFFFFF0000ull) | (k & 0xFFFFull);
      keep = (k48 >= thr48);
    }
    unsigned long long bal = __ballot(keep);
    if (bal) {
      int leader = __ffsll(bal) - 1;
      int basepos = 0;
      if (lane == leader) basepos = atomicAdd(&sh_cnt, (int)__popcll(bal));
      basepos = __shfl(basepos, leader);
      if (keep) {
        int off = __popcll(bal & ((1ull << lane) - 1ull));
        s[basepos + off] = k;
      }
    }
  }
  __syncthreads();
  // phase 3: bitonic sort 8192 descending (filler zeros sink)
  for (int k = 2; k <= 8192; k <<= 1) {
    for (int j = k >> 1; j >= 1; j >>= 1) {
      for (int q = t; q < 4096; q += 1024) {
        int i = ((q & ~(j - 1)) << 1) | (q & (j - 1));
        int pp = i | j;
        bool up = (i & k) == 0;
        unsigned long long a = s[i], d = s[pp];
        if (up ? (a < d) : (a > d)) { s[i] = d; s[pp] = a; }
      }
      __syncthreads();
    }
  }
  // phase 4: gather rank -> box
  for (int e = t; e < PRE; e += 1024) {
    unsigned long long key = s[e];
    unsigned n = ~(unsigned)(key & 0xFFFFFFFFu);
    const float* bx = boxes + ((size_t)b * NA + n) * 4;
    float x1 = bx[0], y1 = bx[1], x2 = bx[2], y2 = bx[3];
    int o = b * PRE + e;
    tbx1[o] = x1; tby1[o] = y1; tbx2[o] = x2; tby2[o] = y2;
    tba[o] = (x2 - x1 + 1.f) * (y2 - y1 + 1.f);
  }
}

// ---------------- NMS suppression bitmask (j > i) — proven round-5 version ----------------
__global__ __launch_bounds__(256) void k_mask(const float* __restrict__ tbx1, const float* __restrict__ tby1,
                                              const float* __restrict__ tbx2, const float* __restrict__ tby2,
                                              const float* __restrict__ tba, unsigned long long* __restrict__ mask) {
  const int b = blockIdx.y;
  const int i0 = blockIdx.x * 64;
  const int t = threadIdx.x;
  __shared__ float jx1[2048], jy1[2048], jx2[2048], jy2[2048], ja[2048];
  __shared__ float ix1[64], iy1[64], ix2[64], iy2[64], ia[64];
  const float* bx1 = tbx1 + b * PRE;
  const float* by1 = tby1 + b * PRE;
  const float* bx2 = tbx2 + b * PRE;
  const float* by2 = tby2 + b * PRE;
  const float* ba2 = tba + b * PRE;
  if (t < 64) {
    int i = i0 + t;
    if (i < PRE) { ix1[t] = bx1[i]; iy1[t] = by1[i]; ix2[t] = bx2[i]; iy2[t] = by2[i]; ia[t] = ba2[i]; }
    else { ix1[t] = 0; iy1[t] = 0; ix2[t] = 0; iy2[t] = 0; ia[t] = 1; }
  }
  for (int c = 0; c < 3; ++c) {
    int j0 = c * 2048;
    for (int e = t; e < 2048; e += 256) {
      int j = j0 + e;
      if (j < PRE) { jx1[e] = bx1[j]; jy1[e] = by1[j]; jx2[e] = bx2[j]; jy2[e] = by2[j]; ja[e] = ba2[j]; }
      else { jx1[e] = 0; jy1[e] = 0; jx2[e] = 0; jy2[e] = 0; ja[e] = 1; }
    }
    __syncthreads();
    for (int task = t; task < 64 * 32; task += 256) {
      int il = task & 63, wl = task >> 6;
      int i = i0 + il;
      int wg = (j0 >> 6) + wl;
      if (i >= PRE || wg >= NW) continue;
      unsigned long long word = 0ull;
      float X1 = ix1[il], Y1 = iy1[il], X2 = ix2[il], Y2 = iy2[il], A = ia[il];
      for (int l = 0; l < 64; ++l) {
        int j = wg * 64 + l;
        if (j > i && j < PRE) {
          int e = j - j0;
          float iw = fminf(X2, jx2[e]) - fmaxf(X1, jx1[e]) + 1.f;
          float ih = fminf(Y2, jy2[e]) - fmaxf(Y1, jy1[e]) + 1.f;
          if (iw > 0.f && ih > 0.f) {
            float inter = iw * ih;
            float iou = inter / (A + ja[e] - inter);
            if (iou > 0.7f) word |= (1ull << l);
          }
        }
      }
      mask[((size_t)(b * PRE + i)) * NW + wg] = word;
    }
    __syncthreads();
  }
}

// ---------------- serial NMS scan (single wave, register-resident) — proven round-5 version ----------------
__global__ void k_nms(const unsigned long long* __restrict__ mask,
                      const float* __restrict__ tbx1, const float* __restrict__ tby1,
                      const float* __restrict__ tbx2, const float* __restrict__ tby2,
                      float* __restrict__ out) {
  const int b = blockIdx.x;
  const int lane = threadIdx.x;  // 64
  unsigned long long rem0 = 0ull;
  unsigned long long rem1;
  if (64 + lane < NW) rem1 = (64 + lane == NW - 1) ? ~((1ull << (PRE - (NW - 1) * 64)) - 1ull) : 0ull;
  else rem1 = ~0ull;
  int sc = 0;
  for (; sc < POST; ++sc) {
    unsigned long long a0 = ~rem0, a1 = ~rem1;
    unsigned long long bal0 = __ballot(a0 != 0ull);
    int w, l;
    if (bal0) {
      int src = __ffsll(bal0) - 1;
      unsigned long long av = __shfl(a0, src);
      w = src; l = __ffsll(av) - 1;
    } else {
      unsigned long long bal1 = __ballot(a1 != 0ull);
      if (!bal1) break;
      int src = __ffsll(bal1) - 1;
      unsigned long long av = __shfl(a1, src);
      w = 64 + src; l = __ffsll(av) - 1;
    }
    int j = w * 64 + l;
    if (lane < 5) {
      float v;
      if (lane == 0) v = (float)b;
      else if (lane == 1) v = tbx1[b * PRE + j];
      else if (lane == 2) v = tby1[b * PRE + j];
      else if (lane == 3) v = tbx2[b * PRE + j];
      else v = tby2[b * PRE + j];
      out[((size_t)(b * POST + sc)) * 5 + lane] = v;
    }
    const unsigned long long* row = mask + ((size_t)(b * PRE + j)) * NW;
    rem0 |= row[lane];
    if (64 + lane < NW) rem1 |= row[64 + lane];
    if (w < 64) { if (lane == w) rem0 |= (1ull << l); }
    else if (lane == w - 64) rem1 |= (1ull << l);
  }
  for (int r2 = sc; r2 < POST; ++r2)
    if (lane < 5) out[((size_t)(b * POST + r2)) * 5 + lane] = (lane == 0) ? (float)b : 0.f;
}

// ---------------- anchor targets: IoU pass (block-aggregated gtmax atomics) — round-13 proven ----------------
__global__ __launch_bounds__(256) void k_iouA(const float* __restrict__ gt_boxes, const float* __restrict__ im_info,
                                              float* __restrict__ iou, float* __restrict__ maxov,
                                              int* __restrict__ argm, unsigned* __restrict__ gtmaxU) {
  const int b = blockIdx.y;
  const int n = blockIdx.x * 256 + threadIdx.x;
  const int t = threadIdx.x, lane = t & 63, wv = t >> 6;
  __shared__ float g[NGT][6];
  __shared__ float wmax[4][NGT];
  if (t < NGT) {
    const float* gg = gt_boxes + (b * NGT + t) * 5;
    float x1 = gg[0], y1 = gg[1], x2 = gg[2], y2 = gg[3];
    g[t][0] = x1; g[t][1] = y1; g[t][2] = x2; g[t][3] = y2;
    float gw = x2 - x1 + 1.f, gh = y2 - y1 + 1.f;
    g[t][4] = gw * gh;
    g[t][5] = ((gw == 1.f) && (gh == 1.f)) ? 0.f : 1.f;
  }
  __syncthreads();
  const bool act = (n < NA);
  float vj[NGT];
  float best = -2.f;
  int barg = 0;
  if (act) {
    int a = n % 9, p = n / 9;
    int h = p / WWW, w = p - h * WWW;
    float ax1 = BA[a][0] + w * 16.f, ay1 = BA[a][1] + h * 16.f;
    float ax2 = BA[a][2] + w * 16.f, ay2 = BA[a][3] + h * 16.f;
    float imh = im_info[b * 3 + 0], imw = im_info[b * 3 + 1];
    bool inside = (ax1 >= 0.f) && (ay1 >= 0.f) && (ax2 < imw) && (ay2 < imh);
    float aw = ax2 - ax1 + 1.f, ah = ay2 - ay1 + 1.f;
    float aa = aw * ah;
    float* row = iou + ((size_t)(b * NA) + n) * NGT;
#pragma unroll
    for (int j = 0; j < NGT; ++j) {
      float iw = fmaxf(fminf(ax2, g[j][2]) - fmaxf(ax1, g[j][0]) + 1.f, 0.f);
      float ih = fmaxf(fminf(ay2, g[j][3]) - fmaxf(ay1, g[j][1]) + 1.f, 0.f);
      float inter = iw * ih;
      float v = inter / (aa + g[j][4] - inter);
      if (g[j][5] == 0.f) v = 0.f;
      if (!inside) v = -1.f;
      row[j] = v;
      vj[j] = v;
      if (v > best) { best = v; barg = j; }
    }
    maxov[b * NA + n] = best;
    argm[b * NA + n] = barg;
  } else {
#pragma unroll
    for (int j = 0; j < NGT; ++j) vj[j] = -1.f;
  }
#pragma unroll
  for (int j = 0; j < NGT; ++j) {
    float red = vj[j];
    for (int o = 32; o > 0; o >>= 1) red = fmaxf(red, __shfl_xor(red, o));
    if (lane == 0) wmax[wv][j] = red;
  }
  __syncthreads();
  if (t < NGT) {
    float m = fmaxf(fmaxf(wmax[0][t], wmax[1][t]), fmaxf(wmax[2][t], wmax[3][t]));
    if (m > 0.f) atomicMax(&gtmaxU[b * NGT + t], monoF(m));
  }
}

// ---------------- labels + sampling keys (reads stored iou: bit-consistent keep-test) ----------------
__global__ __launch_bounds__(256) void k_labels(const float* __restrict__ iou, const float* __restrict__ maxov,
                                                const unsigned* __restrict__ gtmaxU, const float* __restrict__ im_info,
                                                unsigned kf0, unsigned kf1, unsigned kb0, unsigned kb1,
                                                int* __restrict__ labels, unsigned* __restrict__ ufg,
                                                unsigned* __restrict__ ubg, int* __restrict__ cnts) {
  const int b = blockIdx.y;
  const int n = blockIdx.x * 256 + threadIdx.x;
  __shared__ float gmf[NGT];
  if (threadIdx.x < NGT) {
    float gm = unmonoF(gtmaxU[b * NGT + threadIdx.x]);
    gmf[threadIdx.x] = (gm <= 0.f) ? 1e-5f : gm;
  }
  __syncthreads();
  int label = -1;
  if (n < NA) {
    int a = n % 9, p = n / 9;
    int h = p / WWW, w = p - h * WWW;
    float ax1 = BA[a][0] + w * 16.f, ay1 = BA[a][1] + h * 16.f;
    float ax2 = BA[a][2] + w * 16.f, ay2 = BA[a][3] + h * 16.f;
    float imh = im_info[b * 3 + 0], imw = im_info[b * 3 + 1];
    bool inside = (ax1 >= 0.f) && (ay1 >= 0.f) && (ax2 < imw) && (ay2 < imh);
    float mo = maxov[b * NA + n];
    const float* row = iou + ((size_t)(b * NA) + n) * NGT;
    bool keep = false;
#pragma unroll
    for (int j = 0; j < NGT; ++j) keep = keep || (row[j] == gmf[j]);
    if (mo < 0.3f) label = 0;
    if (keep) label = 1;
    if (mo >= 0.7f) label = 1;
    if (!inside) label = -1;
    labels[b * NA + n] = label;
    unsigned pp = (unsigned)(b * NA + n);
    ufg[b * NA + n] = (label == 1) ? tf_u23(kf0, kf1, pp) : 0x00FFFFFFu;
    ubg[b * NA + n] = (label == 0) ? tf_u23(kb0, kb1, pp) : 0x00FFFFFFu;
  }
  unsigned long long bf = __ballot(label == 1);
  unsigned long long bb = __ballot(label == 0);
  if ((threadIdx.x & 63) == 0) {
    atomicAdd(&cnts[b], (int)__popcll(bf));
    atomicAdd(&cnts[4 + b], (int)__popcll(bb));
  }
}

// ---------------- radix rank-k selection for fg/bg sampling (stable, idx tie-break) ----------------
__global__ __launch_bounds__(1024) void k_rsel_samp(const unsigned* __restrict__ ufg, const unsigned* __restrict__ ubg,
                                                    const int* __restrict__ cnts, unsigned* __restrict__ selp,
                                                    float* __restrict__ nexf) {
  const int blk = blockIdx.x;  // 0..7
  const int b = blk >> 1, cls = blk & 1;
  const unsigned* u = (cls == 0 ? ufg : ubg) + (size_t)b * NA;
  const int fcnt = cnts[b], bcnt = cnts[4 + b];
  const int kk = (cls == 0) ? 128 : (256 - (fcnt < 128 ? fcnt : 128));
  const int cnt = (cls == 0) ? fcnt : bcnt;
  const int t = threadIdx.x, wid = t >> 6;
  __shared__ int hist[16][256];
  __shared__ int histT[256];
  __shared__ unsigned long long sh_prefix;
  __shared__ unsigned sh_r;
  if (t == 0) {
    if (cls == 1) {
      int fk = fcnt < 128 ? fcnt : 128;
      int bk2 = bcnt < kk ? bcnt : kk;
      nexf[b] = (float)(fk + bk2);
    }
    sh_prefix = 0ull; sh_r = (unsigned)kk;
  }
  __syncthreads();
  if (kk > cnt) {
    if (t == 0) { selp[blk * 2] = 0x00FFFFFFu; selp[blk * 2 + 1] = 0x1FFFFu; }
    return;
  }
  for (int p = 4; p >= 0; --p) {
    for (int e = t; e < 4096; e += 1024) ((int*)hist)[e] = 0;
    __syncthreads();
    unsigned long long pref = sh_prefix;
    for (int i = t; i < NA; i += 1024) {
      unsigned uv = u[i];
      if (uv == 0x00FFFFFFu) continue;
      unsigned long long k = ((unsigned long long)uv << 17) | (unsigned)i;
      if ((k >> (8 * (p + 1))) == pref)
        atomicAdd(&hist[wid][(int)((k >> (8 * p)) & 255)], 1);
    }
    __syncthreads();
    if (t < 256) { int s = 0; for (int w = 0; w < 16; ++w) s += hist[w][t]; histT[t] = s; }
    __syncthreads();
    if (t == 0) {
      unsigned rr = sh_r; unsigned cum = 0;
      for (int v = 0; v < 256; ++v) {
        cum += (unsigned)histT[v];
        if (cum >= rr) { sh_r = rr - (cum - (unsigned)histT[v]); sh_prefix = (sh_prefix << 8) | (unsigned)v; break; }
      }
    }
    __syncthreads();
  }
  if (t == 0) {
    selp[blk * 2] = (unsigned)(sh_prefix >> 17);
    selp[blk * 2 + 1] = (unsigned)(sh_prefix & 0x1FFFF);
  }
}

// ---------------- losses ----------------
__global__ __launch_bounds__(256) void k_loss(const float* __restrict__ clsS, const float* __restrict__ bbp,
                                              const float* __restrict__ gt_boxes, const int* __restrict__ labels,
                                              const unsigned* __restrict__ ufg, const unsigned* __restrict__ ubg,
                                              const unsigned* __restrict__ selp, const int* __restrict__ argm,
                                              float* __restrict__ accums) {
  const int b = blockIdx.y;
  const int n = blockIdx.x * 256 + threadIdx.x;
  float nll = 0.f, mcnt = 0.f, lbsum = 0.f;
  if (n < NA) {
    int label = labels[b * NA + n];
    int fin = -1;
    if (label == 1) {
      unsigned uu = ufg[b * NA + n];
      unsigned thr = selp[(b * 2 + 0) * 2], ithr = selp[(b * 2 + 0) * 2 + 1];
      if (uu < thr || (uu == thr && (unsigned)n <= ithr)) fin = 1;
    } else if (label == 0) {
      unsigned uu = ubg[b * NA + n];
      unsigned thr = selp[(b * 2 + 1) * 2], ithr = selp[(b * 2 + 1) * 2 + 1];
      if (uu < thr || (uu == thr && (unsigned)n <= ithr)) fin = 0;
    }
    if (fin >= 0) {
      int a = n % 9, p = n / 9;
      float s0 = clsS[((size_t)b * 18 + a) * NPIX + p];
      float s1 = clsS[((size_t)b * 18 + 9 + a) * NPIX + p];
      float mx = fmaxf(s0, s1);
      float lse = mx + logf(expf(s0 - mx) + expf(s1 - mx));
      nll = lse - (fin == 1 ? s1 : s0);
      mcnt = 1.f;
      if (fin == 1) {
        int h = p / WWW, w = p - h * WWW;
        float ax1 = BA[a][0] + w * 16.f, ay1 = BA[a][1] + h * 16.f;
        float ax2 = BA[a][2] + w * 16.f, ay2 = BA[a][3] + h * 16.f;
        float ew = ax2 - ax1 + 1.f, eh = ay2 - ay1 + 1.f;
        float ecx = ax1 + 0.5f * ew, ecy = ay1 + 0.5f * eh;
        int ag = argm[b * NA + n];
        const float* gg = gt_boxes + (b * NGT + ag) * 5;
        float gw = gg[2] - gg[0] + 1.f, gh = gg[3] - gg[1] + 1.f;
        float gcx = gg[0] + 0.5f * gw, gcy = gg[1] + 0.5f * gh;
        float tt[4];
        tt[0] = (gcx - ecx) / ew;
        tt[1] = (gcy - ecy) / eh;
        tt[2] = logf(gw / ew);
        tt[3] = logf(gh / eh);
#pragma unroll
        for (int dd = 0; dd < 4; ++dd) {
          float pd = bbp[((size_t)b * 36 + (a * 4 + dd)) * NPIX + p];
          float diff = pd - tt[dd];
          float ad = fabsf(diff);
          lbsum += (ad < 1.f / 9.f) ? 4.5f * diff * diff : (ad - 0.5f / 9.f);
        }
      }
    }
  }
  for (int o = 32; o > 0; o >>= 1) {
    nll += __shfl_down(nll, o);
    mcnt += __shfl_down(mcnt, o);
    lbsum += __shfl_down(lbsum, o);
  }
  __shared__ float p0[4], p1[4], p2[4];
  int wid = threadIdx.x >> 6;
  if ((threadIdx.x & 63) == 0) { p0[wid] = nll; p1[wid] = mcnt; p2[wid] = lbsum; }
  __syncthreads();
  if (threadIdx.x == 0) {
    float aS = 0, bS = 0, cS = 0;
    for (int q = 0; q < 4; ++q) { aS += p0[q]; bS += p1[q]; cS += p2[q]; }
    atomicAdd(&accums[0], aS);
    atomicAdd(&accums[1], bS);
    atomicAdd(&accums[2 + b], cS);
  }
}

__global__ void k_final(const float* __restrict__ accums, const float* __restrict__ nexf, float* __restrict__ out) {
  if (threadIdx.x == 0 && blockIdx.x == 0) {
    out[6000] = accums[0] / accums[1];
    float lb = 0.f;
    for (int b = 0; b < NBATCH; ++b) lb += accums[2 + b] / nexf[b];
    out[6001] = lb * 0.25f;
  }
}

// ---------------- host ----------------
extern "C" void kernel_launch(void* const* d_in, const int* in_sizes, int n_in,
                              void* d_out, int out_size, void* d_ws, size_t ws_size,
                              hipStream_t stream) {
  (void)in_sizes; (void)n_in; (void)out_size; (void)ws_size;
  const float* base_feat = (const float*)d_in[0];
  const float* im_info   = (const float*)d_in[1];
  const float* gt_boxes  = (const float*)d_in[2];
  const float* conv_w    = (const float*)d_in[4];
  const float* conv_b    = (const float*)d_in[5];
  const float* cls_w     = (const float*)d_in[6];
  const float* cls_b     = (const float*)d_in[7];
  const float* bbox_w    = (const float*)d_in[8];
  const float* bbox_b    = (const float*)d_in[9];
  float* out = (float*)d_out;

  char* wp = (char*)d_ws;
  auto carve = [&](size_t bytes) -> void* {
    void* r = (void*)wp;
    wp += (bytes + 255) & ~(size_t)255;
    return r;
  };
  // region A: live across both phases
  float* x     = (float*)carve((size_t)NBATCH * CIN * NPIX * 4);
  float* clsS  = (float*)carve((size_t)NBATCH * 18 * NPIX * 4);
  float* bbp   = (float*)carve((size_t)NBATCH * 36 * NPIX * 4);
  unsigned short* WT0 = (unsigned short*)carve((size_t)9 * 64 * 512 * 8 * 2);
  unsigned short* WT1 = (unsigned short*)carve((size_t)9 * 64 * 512 * 8 * 2);
  unsigned short* WT2 = (unsigned short*)carve((size_t)9 * 64 * 512 * 8 * 2);
  float* wt1   = (float*)carve((size_t)CIN * 64 * 4);
  unsigned* gtmaxU = (unsigned*)carve(NBATCH * NGT * 4);
  int* cnts    = (int*)carve(8 * 4);
  unsigned* selp = (unsigned*)carve(16 * 4);
  float* nexf  = (float*)carve(4 * 4);
  float* accums = (float*)carve(8 * 4);

  // region B: X splits (conv3 phase) overlaid with post-conv buffers
  char* overlay = wp;
  unsigned short* XT0 = (unsigned short*)overlay;
  unsigned short* XT1 = XT0 + (size_t)NBATCH * XTB;
  unsigned short* XT2 = XT1 + (size_t)NBATCH * XTB;
  char* wp2 = overlay;
  auto carve2 = [&](size_t bytes) -> void* {
    void* r = (void*)wp2;
    wp2 += (bytes + 255) & ~(size_t)255;
    return r;
  };
  float* boxes = (float*)carve2((size_t)NBATCH * NA * 4 * 4);
  unsigned long long* keys = (unsigned long long*)carve2((size_t)NBATCH * 65536 * 8);
  float* tbx1 = (float*)carve2((size_t)NBATCH * PRE * 4);
  float* tby1 = (float*)carve2((size_t)NBATCH * PRE * 4);
  float* tbx2 = (float*)carve2((size_t)NBATCH * PRE * 4);
  float* tby2 = (float*)carve2((size_t)NBATCH * PRE * 4);
  float* tba  = (float*)carve2((size_t)NBATCH * PRE * 4);
  unsigned long long* mask = (unsigned long long*)carve2((size_t)NBATCH * PRE * NW * 8);
  float* iou   = (float*)carve2((size_t)NBATCH * NA * NGT * 4);
  float* maxov = (float*)carve2((size_t)NBATCH * NA * 4);
  int* argm    = (int*)carve2((size_t)NBATCH * NA * 4);
  int* labels  = (int*)carve2((size_t)NBATCH * NA * 4);
  unsigned* ufg = (unsigned*)carve2((size_t)NBATCH * NA * 4);
  unsigned* ubg = (unsigned*)carve2((size_t)NBATCH * NA * 4);

  // rbg key = threefry_fold_in(key(42), 1)
  unsigned kb0 = 0u, kb1 = 1u;
  tf2x32(0u, 42u, kb0, kb1);

  k_split_w<<<dim3((9 * 64 * 512 * 8) / 256), dim3(256), 0, stream>>>(conv_w, WT0, WT1, WT2, gtmaxU, cnts, accums);
  k_tr_w1<<<dim3((CIN * 64) / 256), dim3(256), 0, stream>>>(cls_w, bbox_w, wt1);
  k_split_x<<<dim3((NBATCH * XTB + 255) / 256), dim3(256), 0, stream>>>(base_feat, XT0, XT1, XT2);
  k_conv3<<<dim3(1024), dim3(256), 0, stream>>>(XT0, XT1, XT2, WT0, WT1, WT2, conv_b, x);
  k_conv1<<<dim3(30, 4), dim3(256), 0, stream>>>(x, wt1, cls_b, bbox_b, clsS, bbp);
  k_decode<<<dim3((NBATCH * NA + 255) / 256), dim3(256), 0, stream>>>(clsS, bbp, im_info, boxes, keys);
  k_rsel_sort<<<dim3(NBATCH), dim3(1024), 0, stream>>>(keys, boxes, tbx1, tby1, tbx2, tby2, tba);
  k_mask<<<dim3(NW, NBATCH), dim3(256), 0, stream>>>(tbx1, tby1, tbx2, tby2, tba, mask);
  k_nms<<<dim3(NBATCH), dim3(64), 0, stream>>>(mask, tbx1, tby1, tbx2, tby2, out);
  k_iouA<<<dim3((NA + 255) / 256, NBATCH), dim3(256), 0, stream>>>(gt_boxes, im_info, iou, maxov, argm, gtmaxU);
  k_labels<<<dim3((NA + 255) / 256, NBATCH), dim3(256), 0, stream>>>(iou, maxov, gtmaxU, im_info,
                                                                     0u, 42u, kb0, kb1, labels, ufg, ubg, cnts);
  k_rsel_samp<<<dim3(8), dim3(1024), 0, stream>>>(ufg, ubg, cnts, selp, nexf);
  k_loss<<<dim3((NA + 255) / 256, NBATCH), dim3(256), 0, stream>>>(clsS, bbp, gt_boxes, labels, ufg, ubg, selp, argm, accums);
  k_final<<<dim3(1), dim3(1), 0, stream>>>(accums, nexf, out);
}